// Round 11
// baseline (229.258 us; speedup 1.0000x reference)
//
#include <hip/hip_runtime.h>
#include <hip/hip_fp16.h>
#include <cstdint>
#include <cstddef>

#define NUM_REL 20000
#define NUM_EDGES 640000
#define DIM_IN 128
#define DIM_OUT 256
#define NUM_HEAD 8
#define DIM_HID 32
#define NUM_BIN 10
#define CAP 192  // fixed bucket capacity (max degree ~65 for Poisson(32); 28-sigma margin)

// P16 row (768 halves): [0,256) = ZH (plain);
// [256,768) = interleaved quads: quad q: ZT[4q..4q+4) at 256+8q, MSG[4q..4q+4) at 260+8q.
// -> edge kernel reads ONE uint4 per lane per edge.

typedef _Float16 f16x8 __attribute__((ext_vector_type(8)));
typedef _Float16 h2 __attribute__((ext_vector_type(2)));
typedef float f32x4 __attribute__((ext_vector_type(4)));

union H2U { unsigned u; h2 h; };

// ---------------------------------------------------------------------------
// Prep: blocks [0,20) zero cursor (20480 ints, int4 stores);
//       blocks [20,116) convert combined weights to fp16 Bh[o][k] (o<768,k<128).
// ---------------------------------------------------------------------------
__global__ __launch_bounds__(256) void prep_kernel(
    const float* __restrict__ attn_w, const float* __restrict__ aggr_w,
    __half* __restrict__ Bh, int* __restrict__ cursor) {
  const int b = blockIdx.x, tid = threadIdx.x;
  if (b < 20) {
    int idx = b * 1024 + tid * 4;
    *(int4*)(cursor + idx) = make_int4(0, 0, 0, 0);
    return;
  }
  int i = (b - 20) * 256 + tid;  // [0, 24576): one float4 per thread
  int o = (i * 4) >> 7;
  int k = (i * 4) & 127;
  float4 v;
  if (o < 256)      v = *(const float4*)(attn_w + (size_t)o * 256 + k);
  else if (o < 512) v = *(const float4*)(attn_w + (size_t)(o - 256) * 256 + 128 + k);
  else              v = *(const float4*)(aggr_w + (size_t)(o - 512) * 128 + k);
  __half2 h0 = __floats2half2_rn(v.x, v.y);
  __half2 h1 = __floats2half2_rn(v.z, v.w);
  uint2 u;
  u.x = *(unsigned*)&h0;
  u.y = *(unsigned*)&h1;
  *(uint2*)(Bh + (size_t)o * 128 + k) = u;
}

// ---------------------------------------------------------------------------
// Work: blocks [0,1250) = MFMA GEMM (operand-swapped, packed uint2 stores into
// interleaved P16); blocks [1250,3750) = bucket fill (atomic slot in fixed-CAP
// bucket). Independent tasks, both depend only on prep.
// ---------------------------------------------------------------------------
__global__ __launch_bounds__(256) void work_kernel(
    const float* __restrict__ emb, const __half* __restrict__ Bh,
    const float* __restrict__ attn_b, const float* __restrict__ aggr_b,
    __half* __restrict__ P16, const int* __restrict__ trip,
    int* __restrict__ cursor, int* __restrict__ tbsorted) {
  __shared__ float biasF[768];
  const int tid = threadIdx.x;

  if (blockIdx.x >= 1250) {  // ---- fill ----
    int e = (blockIdx.x - 1250) * 256 + tid;  // exactly covers [0, 640000)
    int hd = trip[e * 3 + 0];
    int tl = trip[e * 3 + 1];
    int bn = trip[e * 3 + 2];
    int pos = atomicAdd(&cursor[hd], 1);
    if (pos < CAP) tbsorted[hd * CAP + pos] = tl | (bn << 15);
    return;
  }

  // ---- GEMM ----
  const int w = tid >> 6, l = tid & 63;
  const int m0 = (blockIdx.x >> 1) * 32;
  const int half_ = blockIdx.x & 1;
  const int lr = l & 15, lk = l >> 4;

  for (int c = tid; c < 768; c += 256) {
    float b = 0.f;
    if (c >= 512)      b = aggr_b[c - 512];
    else if (c >= 256) b = attn_b[c - 256];
    biasF[c] = b;
  }
  __syncthreads();

  // emb fragments (B-operand): rel = m0 + rt*16 + lr, k = kt*32 + lk*8 + j
  f16x8 a[2][4];
  #pragma unroll
  for (int rt = 0; rt < 2; ++rt) {
    const float* src = emb + (size_t)(m0 + rt * 16 + lr) * 128 + lk * 8;
    #pragma unroll
    for (int kt = 0; kt < 4; ++kt) {
      float4 f0 = *(const float4*)(src + kt * 32);
      float4 f1 = *(const float4*)(src + kt * 32 + 4);
      f16x8 v;
      v[0] = (_Float16)f0.x; v[1] = (_Float16)f0.y; v[2] = (_Float16)f0.z; v[3] = (_Float16)f0.w;
      v[4] = (_Float16)f1.x; v[5] = (_Float16)f1.y; v[6] = (_Float16)f1.z; v[7] = (_Float16)f1.w;
      a[rt][kt] = v;
    }
  }

  const int colbase = half_ * 384 + w * 96;
  #pragma unroll 1
  for (int ct = 0; ct < 6; ++ct) {
    const int c0 = colbase + ct * 16;
    const int col = c0 + lr;  // weight row (A-operand index)
    f16x8 bw[4];
    const __half* bsrc = Bh + (size_t)col * 128 + lk * 8;
    #pragma unroll
    for (int kt = 0; kt < 4; ++kt)
      bw[kt] = *reinterpret_cast<const f16x8*>(bsrc + kt * 32);
    f32x4 acc0 = {0.f, 0.f, 0.f, 0.f};
    f32x4 acc1 = {0.f, 0.f, 0.f, 0.f};
    #pragma unroll
    for (int kt = 0; kt < 4; ++kt) {
      acc0 = __builtin_amdgcn_mfma_f32_16x16x32_f16(bw[kt], a[0][kt], acc0, 0, 0, 0);
      acc1 = __builtin_amdgcn_mfma_f32_16x16x32_f16(bw[kt], a[1][kt], acc1, 0, 0, 0);
    }
    // lane holds cols cq..cq+3 of relation rows (m0+lr) and (m0+16+lr)
    const int cq = c0 + lk * 4;
    int d;
    if (cq < 256)      d = cq;
    else if (cq < 512) d = 256 + ((cq - 256) >> 2) * 8;
    else               d = 260 + ((cq - 512) >> 2) * 8;
    float4 bb = *(const float4*)&biasF[cq];
    __half2 h0 = __floats2half2_rn(acc0[0] + bb.x, acc0[1] + bb.y);
    __half2 h1 = __floats2half2_rn(acc0[2] + bb.z, acc0[3] + bb.w);
    uint2 u0; u0.x = *(unsigned*)&h0; u0.y = *(unsigned*)&h1;
    *(uint2*)(P16 + (size_t)(m0 + lr) * 768 + d) = u0;
    h0 = __floats2half2_rn(acc1[0] + bb.x, acc1[1] + bb.y);
    h1 = __floats2half2_rn(acc1[2] + bb.z, acc1[3] + bb.w);
    uint2 u1; u1.x = *(unsigned*)&h0; u1.y = *(unsigned*)&h1;
    *(uint2*)(P16 + (size_t)(m0 + 16 + lr) * 768 + d) = u1;
  }
}

// ---------------------------------------------------------------------------
// Wave-per-relation fused edge kernel, fixed-max softmax (logits bounded ->
// exp(raw) directly; o/S identical to max-subtracted form). Per edge: one
// uint4 gather (interleaved ZT|MSG), packed-fp16 logit, 1 exp, 4 FMA accum.
// No inter-wave merge, no barriers after bin staging.
// ---------------------------------------------------------------------------
__global__ __launch_bounds__(256) void edge_agg_kernel(
    const __half* __restrict__ P16, const int* __restrict__ tbsorted,
    const int* __restrict__ cursor, const float* __restrict__ attn_bin,
    const float* __restrict__ attn_vec, float* __restrict__ out) {
  __shared__ float binS[NUM_BIN][8];
  const int tid = threadIdx.x;
  if (tid < NUM_BIN * 8) binS[tid >> 3][tid & 7] = attn_bin[tid];
  __syncthreads();

  const int lane = tid & 63;
  const int w = tid >> 6;
  const int r = blockIdx.x * 4 + w;  // one relation per wave
  const int h = lane >> 3;
  int n = cursor[r];
  n = n < CAP ? n : CAP;
  if (n == 0) {
    *(float4*)(out + (size_t)r * 256 + lane * 4) = make_float4(0.f, 0.f, 0.f, 0.f);
    return;
  }

  float4 vvf = *(const float4*)(attn_vec + lane * 4);
  h2 vv0 = {(_Float16)vvf.x, (_Float16)vvf.y};
  h2 vv1 = {(_Float16)vvf.z, (_Float16)vvf.w};
  const uint2 zhu = *(const uint2*)(P16 + (size_t)r * 768 + lane * 4);
  H2U zh0, zh1; zh0.u = zhu.x; zh1.u = zhu.y;
  const h2 c06 = {(_Float16)0.6f, (_Float16)0.6f};
  const h2 c04 = {(_Float16)0.4f, (_Float16)0.4f};
  const char* base = (const char*)P16;
  const unsigned laneoff = 512u + (unsigned)lane * 16u;
  const int* tbs = tbsorted + r * CAP;

  float s = 0.f;
  float4 acc = make_float4(0.f, 0.f, 0.f, 0.f);

  unsigned tb0 = (unsigned)tbs[0];
  uint4 r0 = *(const uint4*)(base + (tb0 & 0x7fffu) * 1536u + laneoff);
  for (int i = 0; i < n; ++i) {
    unsigned tb1 = 0u;
    uint4 r1 = r0;
    if (i + 1 < n) {  // wave-uniform guard; prefetch next edge
      tb1 = (unsigned)tbs[i + 1];
      r1 = *(const uint4*)(base + (tb1 & 0x7fffu) * 1536u + laneoff);
    }
    // logit
    int bn = (int)(tb0 >> 15);
    H2U a0, a1; a0.u = r0.x; a1.u = r0.y;
    h2 z0 = zh0.h + a0.h;
    h2 z1 = zh1.h + a1.h;
    H2U b0, b1; b0.h = z0; b1.h = z1;
    b0.u &= 0x7FFF7FFFu; b1.u &= 0x7FFF7FFFu;  // |x|
    h2 l0 = z0 * c06 + b0.h * c04;             // leakyrelu(x,0.2)=0.6x+0.4|x|
    h2 l1 = z1 * c06 + b1.h * c04;
    float p = __builtin_amdgcn_fdot2(l0, vv0, 0.f, false);
    p = __builtin_amdgcn_fdot2(l1, vv1, p, false);
    p += __shfl_xor(p, 1);
    p += __shfl_xor(p, 2);
    p += __shfl_xor(p, 4);  // all lanes of the 8-group hold the head dot
    float raw = fminf(p + binS[bn][h], 60.f);
    // fixed-max softmax accumulation
    float wv = __expf(raw);
    s += wv;
    float2 g0 = __half22float2(*(const __half2*)&r0.z);
    float2 g1 = __half22float2(*(const __half2*)&r0.w);
    acc.x += wv * g0.x;
    acc.y += wv * g0.y;
    acc.z += wv * g1.x;
    acc.w += wv * g1.y;
    tb0 = tb1; r0 = r1;
  }

  float inv = 1.f / (s + 1e-16f);
  float4 o4 = make_float4(acc.x * inv, acc.y * inv, acc.z * inv, acc.w * inv);
  *(float4*)(out + (size_t)r * 256 + lane * 4) = o4;
}

extern "C" void kernel_launch(void* const* d_in, const int* in_sizes, int n_in,
                              void* d_out, int out_size, void* d_ws, size_t ws_size,
                              hipStream_t stream) {
  const float* emb      = (const float*)d_in[0];
  const int*   trip     = (const int*)d_in[1];
  const float* attn_w   = (const float*)d_in[2];
  const float* attn_b   = (const float*)d_in[3];
  const float* attn_bin = (const float*)d_in[4];
  const float* attn_vec = (const float*)d_in[5];
  const float* aggr_w   = (const float*)d_in[6];
  const float* aggr_b   = (const float*)d_in[7];
  float* out = (float*)d_out;

  // workspace layout (~46.4 MB)
  __half* P16   = (__half*)d_ws;                          // 20000*768 f16
  __half* Bh    = P16 + (size_t)NUM_REL * 768;            // 768*128 f16
  int* tbsorted = (int*)(Bh + 768 * 128);                 // 20000*192 i32 (fixed-CAP buckets)
  int* cursor   = tbsorted + (size_t)NUM_REL * CAP;       // 20480 i32 (doubles as count)

  hipLaunchKernelGGL(prep_kernel, dim3(116), dim3(256), 0, stream,
                     attn_w, aggr_w, Bh, cursor);
  hipLaunchKernelGGL(work_kernel, dim3(1250 + 2500), dim3(256), 0, stream,
                     emb, Bh, attn_b, aggr_b, P16, trip, cursor, tbsorted);
  hipLaunchKernelGGL(edge_agg_kernel, dim3(NUM_REL / 4), dim3(256), 0, stream,
                     P16, tbsorted, cursor, attn_bin, attn_vec, out);
}

// Round 12
// 213.552 us; speedup vs baseline: 1.0735x; 1.0735x over previous
//
#include <hip/hip_runtime.h>
#include <hip/hip_fp16.h>
#include <cstdint>
#include <cstddef>

#define NUM_REL 20000
#define NUM_EDGES 640000
#define DIM_IN 128
#define DIM_OUT 256
#define NUM_HEAD 8
#define DIM_HID 32
#define NUM_BIN 10
#define CAP 192  // fixed bucket capacity (max degree ~65 for Poisson(32); 28-sigma margin)

// P16 row (768 halves): [0,256) = ZH (plain);
// [256,768) = interleaved quads: quad q: ZT[4q..4q+4) at 256+8q, MSG[4q..4q+4) at 260+8q.
// -> edge kernel reads ONE uint4 per lane per edge.

typedef _Float16 f16x8 __attribute__((ext_vector_type(8)));
typedef _Float16 h2 __attribute__((ext_vector_type(2)));
typedef float f32x4 __attribute__((ext_vector_type(4)));

union H2U { unsigned u; h2 h; };

// ---------------------------------------------------------------------------
// Prep: blocks [0,20) zero cursor (20480 ints, int4 stores);
//       blocks [20,116) convert combined weights to fp16 Bh[o][k] (o<768,k<128).
// ---------------------------------------------------------------------------
__global__ __launch_bounds__(256) void prep_kernel(
    const float* __restrict__ attn_w, const float* __restrict__ aggr_w,
    __half* __restrict__ Bh, int* __restrict__ cursor) {
  const int b = blockIdx.x, tid = threadIdx.x;
  if (b < 20) {
    int idx = b * 1024 + tid * 4;
    *(int4*)(cursor + idx) = make_int4(0, 0, 0, 0);
    return;
  }
  int i = (b - 20) * 256 + tid;  // [0, 24576): one float4 per thread
  int o = (i * 4) >> 7;
  int k = (i * 4) & 127;
  float4 v;
  if (o < 256)      v = *(const float4*)(attn_w + (size_t)o * 256 + k);
  else if (o < 512) v = *(const float4*)(attn_w + (size_t)(o - 256) * 256 + 128 + k);
  else              v = *(const float4*)(aggr_w + (size_t)(o - 512) * 128 + k);
  __half2 h0 = __floats2half2_rn(v.x, v.y);
  __half2 h1 = __floats2half2_rn(v.z, v.w);
  uint2 u;
  u.x = *(unsigned*)&h0;
  u.y = *(unsigned*)&h1;
  *(uint2*)(Bh + (size_t)o * 128 + k) = u;
}

// ---------------------------------------------------------------------------
// Work: blocks [0,1250) = MFMA GEMM (operand-swapped, packed uint2 stores into
// interleaved P16); blocks [1250,3750) = bucket fill (atomic slot in fixed-CAP
// bucket). Independent tasks, both depend only on prep.
// ---------------------------------------------------------------------------
__global__ __launch_bounds__(256) void work_kernel(
    const float* __restrict__ emb, const __half* __restrict__ Bh,
    const float* __restrict__ attn_b, const float* __restrict__ aggr_b,
    __half* __restrict__ P16, const int* __restrict__ trip,
    int* __restrict__ cursor, int* __restrict__ tbsorted) {
  __shared__ float biasF[768];
  const int tid = threadIdx.x;

  if (blockIdx.x >= 1250) {  // ---- fill ----
    int e = (blockIdx.x - 1250) * 256 + tid;  // exactly covers [0, 640000)
    int hd = trip[e * 3 + 0];
    int tl = trip[e * 3 + 1];
    int bn = trip[e * 3 + 2];
    int pos = atomicAdd(&cursor[hd], 1);
    if (pos < CAP) tbsorted[hd * CAP + pos] = tl | (bn << 15);
    return;
  }

  // ---- GEMM ----
  const int w = tid >> 6, l = tid & 63;
  const int m0 = (blockIdx.x >> 1) * 32;
  const int half_ = blockIdx.x & 1;
  const int lr = l & 15, lk = l >> 4;

  for (int c = tid; c < 768; c += 256) {
    float b = 0.f;
    if (c >= 512)      b = aggr_b[c - 512];
    else if (c >= 256) b = attn_b[c - 256];
    biasF[c] = b;
  }
  __syncthreads();

  // emb fragments (B-operand): rel = m0 + rt*16 + lr, k = kt*32 + lk*8 + j
  f16x8 a[2][4];
  #pragma unroll
  for (int rt = 0; rt < 2; ++rt) {
    const float* src = emb + (size_t)(m0 + rt * 16 + lr) * 128 + lk * 8;
    #pragma unroll
    for (int kt = 0; kt < 4; ++kt) {
      float4 f0 = *(const float4*)(src + kt * 32);
      float4 f1 = *(const float4*)(src + kt * 32 + 4);
      f16x8 v;
      v[0] = (_Float16)f0.x; v[1] = (_Float16)f0.y; v[2] = (_Float16)f0.z; v[3] = (_Float16)f0.w;
      v[4] = (_Float16)f1.x; v[5] = (_Float16)f1.y; v[6] = (_Float16)f1.z; v[7] = (_Float16)f1.w;
      a[rt][kt] = v;
    }
  }

  const int colbase = half_ * 384 + w * 96;
  #pragma unroll 1
  for (int ct = 0; ct < 6; ++ct) {
    const int c0 = colbase + ct * 16;
    const int col = c0 + lr;  // weight row (A-operand index)
    f16x8 bw[4];
    const __half* bsrc = Bh + (size_t)col * 128 + lk * 8;
    #pragma unroll
    for (int kt = 0; kt < 4; ++kt)
      bw[kt] = *reinterpret_cast<const f16x8*>(bsrc + kt * 32);
    f32x4 acc0 = {0.f, 0.f, 0.f, 0.f};
    f32x4 acc1 = {0.f, 0.f, 0.f, 0.f};
    #pragma unroll
    for (int kt = 0; kt < 4; ++kt) {
      acc0 = __builtin_amdgcn_mfma_f32_16x16x32_f16(bw[kt], a[0][kt], acc0, 0, 0, 0);
      acc1 = __builtin_amdgcn_mfma_f32_16x16x32_f16(bw[kt], a[1][kt], acc1, 0, 0, 0);
    }
    // lane holds cols cq..cq+3 of relation rows (m0+lr) and (m0+16+lr)
    const int cq = c0 + lk * 4;
    int d;
    if (cq < 256)      d = cq;
    else if (cq < 512) d = 256 + ((cq - 256) >> 2) * 8;
    else               d = 260 + ((cq - 512) >> 2) * 8;
    float4 bb = *(const float4*)&biasF[cq];
    __half2 h0 = __floats2half2_rn(acc0[0] + bb.x, acc0[1] + bb.y);
    __half2 h1 = __floats2half2_rn(acc0[2] + bb.z, acc0[3] + bb.w);
    uint2 u0; u0.x = *(unsigned*)&h0; u0.y = *(unsigned*)&h1;
    *(uint2*)(P16 + (size_t)(m0 + lr) * 768 + d) = u0;
    h0 = __floats2half2_rn(acc1[0] + bb.x, acc1[1] + bb.y);
    h1 = __floats2half2_rn(acc1[2] + bb.z, acc1[3] + bb.w);
    uint2 u1; u1.x = *(unsigned*)&h0; u1.y = *(unsigned*)&h1;
    *(uint2*)(P16 + (size_t)(m0 + 16 + lr) * 768 + d) = u1;
  }
}

// ---------------------------------------------------------------------------
// Block-per-relation fused edge kernel, fixed-max softmax, depth-2 pipeline.
// 4 waves x stride-4 edges; per edge one uint4 gather (interleaved ZT|MSG),
// packed-fp16 logit, 1 exp, 4 FMA. Tails prefetched 3 iters ahead, rows 2
// ahead (two 1KB gathers in flight per wave). Merge = pure sums (no max).
// ---------------------------------------------------------------------------
__global__ __launch_bounds__(256) void edge_agg_kernel(
    const __half* __restrict__ P16, const int* __restrict__ tbsorted,
    const int* __restrict__ cursor, const float* __restrict__ attn_bin,
    const float* __restrict__ attn_vec, float* __restrict__ out) {
  __shared__ float binS[NUM_BIN][8];
  __shared__ float sS[4][8];
  __shared__ float accS[4][256];
  const int r = blockIdx.x;
  const int tid = threadIdx.x;
  if (tid < NUM_BIN * 8) binS[tid >> 3][tid & 7] = attn_bin[tid];
  __syncthreads();

  int n = cursor[r];
  n = n < CAP ? n : CAP;
  if (n == 0) {
    out[(size_t)r * 256 + tid] = 0.f;
    return;
  }
  const int lane = tid & 63;
  const int w = tid >> 6;
  const int h = lane >> 3;

  float4 vvf = *(const float4*)(attn_vec + lane * 4);
  h2 vv0 = {(_Float16)vvf.x, (_Float16)vvf.y};
  h2 vv1 = {(_Float16)vvf.z, (_Float16)vvf.w};
  const uint2 zhu = *(const uint2*)(P16 + (size_t)r * 768 + lane * 4);
  H2U zh0, zh1; zh0.u = zhu.x; zh1.u = zhu.y;
  const h2 c06 = {(_Float16)0.6f, (_Float16)0.6f};
  const h2 c04 = {(_Float16)0.4f, (_Float16)0.4f};
  const char* base = (const char*)P16;
  const unsigned laneoff = 512u + (unsigned)lane * 16u;
  const int* tbs = tbsorted + r * CAP;

  float s = 0.f;
  float4 acc = make_float4(0.f, 0.f, 0.f, 0.f);

  // pipeline init: tails up to 2 strides ahead, rows up to 2 in flight
  unsigned tb0 = 0u, tb1 = 0u, tb2 = 0u;
  uint4 r0 = make_uint4(0u, 0u, 0u, 0u), r1 = r0;
  if (w < n) {
    tb0 = (unsigned)tbs[w];
    r0 = *(const uint4*)(base + (tb0 & 0x7fffu) * 1536u + laneoff);
  }
  if (w + 4 < n) {
    tb1 = (unsigned)tbs[w + 4];
    r1 = *(const uint4*)(base + (tb1 & 0x7fffu) * 1536u + laneoff);
  }
  if (w + 8 < n) tb2 = (unsigned)tbs[w + 8];

  for (int i = w; i < n; i += 4) {
    unsigned tb3 = (i + 12 < n) ? (unsigned)tbs[i + 12] : 0u;
    uint4 r2 = r0;
    if (i + 8 < n) r2 = *(const uint4*)(base + (tb2 & 0x7fffu) * 1536u + laneoff);
    // ---- process edge i (tb0, r0) ----
    int bn = (int)(tb0 >> 15);
    H2U a0, a1; a0.u = r0.x; a1.u = r0.y;
    h2 z0 = zh0.h + a0.h;
    h2 z1 = zh1.h + a1.h;
    H2U b0, b1; b0.h = z0; b1.h = z1;
    b0.u &= 0x7FFF7FFFu; b1.u &= 0x7FFF7FFFu;  // |x|
    h2 l0 = z0 * c06 + b0.h * c04;             // leakyrelu(x,0.2)=0.6x+0.4|x|
    h2 l1 = z1 * c06 + b1.h * c04;
    float p = __builtin_amdgcn_fdot2(l0, vv0, 0.f, false);
    p = __builtin_amdgcn_fdot2(l1, vv1, p, false);
    p += __shfl_xor(p, 1);
    p += __shfl_xor(p, 2);
    p += __shfl_xor(p, 4);  // all lanes of the 8-group hold the head dot
    float raw = fminf(p + binS[bn][h], 60.f);
    float wv = __expf(raw);  // fixed-max softmax (logits bounded)
    s += wv;
    float2 g0 = __half22float2(*(const __half2*)&r0.z);
    float2 g1 = __half22float2(*(const __half2*)&r0.w);
    acc.x += wv * g0.x;
    acc.y += wv * g0.y;
    acc.z += wv * g1.x;
    acc.w += wv * g1.y;
    // shift pipeline
    tb0 = tb1; tb1 = tb2; tb2 = tb3; r0 = r1; r1 = r2;
  }

  // ---- 4-wave merge: pure sums ----
  if ((lane & 7) == 0) sS[w][h] = s;
  *(float4*)&accS[w][lane * 4] = acc;
  __syncthreads();

  const int hh = tid >> 5;  // output col = tid, head = tid>>5
  float S = sS[0][hh] + sS[1][hh] + sS[2][hh] + sS[3][hh];
  float o = accS[0][tid] + accS[1][tid] + accS[2][tid] + accS[3][tid];
  out[(size_t)r * 256 + tid] = o / (S + 1e-16f);
}

extern "C" void kernel_launch(void* const* d_in, const int* in_sizes, int n_in,
                              void* d_out, int out_size, void* d_ws, size_t ws_size,
                              hipStream_t stream) {
  const float* emb      = (const float*)d_in[0];
  const int*   trip     = (const int*)d_in[1];
  const float* attn_w   = (const float*)d_in[2];
  const float* attn_b   = (const float*)d_in[3];
  const float* attn_bin = (const float*)d_in[4];
  const float* attn_vec = (const float*)d_in[5];
  const float* aggr_w   = (const float*)d_in[6];
  const float* aggr_b   = (const float*)d_in[7];
  float* out = (float*)d_out;

  // workspace layout (~46.4 MB)
  __half* P16   = (__half*)d_ws;                          // 20000*768 f16
  __half* Bh    = P16 + (size_t)NUM_REL * 768;            // 768*128 f16
  int* tbsorted = (int*)(Bh + 768 * 128);                 // 20000*192 i32 (fixed-CAP buckets)
  int* cursor   = tbsorted + (size_t)NUM_REL * CAP;       // 20480 i32 (doubles as count)

  hipLaunchKernelGGL(prep_kernel, dim3(116), dim3(256), 0, stream,
                     attn_w, aggr_w, Bh, cursor);
  hipLaunchKernelGGL(work_kernel, dim3(1250 + 2500), dim3(256), 0, stream,
                     emb, Bh, attn_b, aggr_b, P16, trip, cursor, tbsorted);
  hipLaunchKernelGGL(edge_agg_kernel, dim3(NUM_REL), dim3(256), 0, stream,
                     P16, tbsorted, cursor, attn_bin, attn_vec, out);
}